// Round 15
// baseline (328.297 us; speedup 1.0000x reference)
//
#include <hip/hip_runtime.h>

#define N_NODES 50000
#define N_EDGES 800000
#define IN_F    128
#define OUT_F   128
#define NEIG    64
#define HDIM    128
#define BN_EPSF 1e-5f
#define XB_ROWS 50048            // 50000 padded to 128
#define XB_COLS 640
#define SCAN_BLK 49              // ceil(50000/1024)
#define HSP_BLOCKS 521           // 521*96 >= 50000
#define HSP_NODES 96
#define RED_CHUNK 33             // ceil(521/16)
#define N_CHK 64                 // edge chunks (R15: 32->64; 256 rank blocks kill the tail)
#define N_RNG 4                  // node ranges (12500 nodes -> 25KB LDS counters)
#define RANKB (N_RNG * N_CHK)    // 256 rank blocks
#define CHUNK_E (N_EDGES / N_CHK) // 12500 edges per chunk

// stage2 block-range bounds (hs | mlp | rank | prep-wt | prep-zero)
#define S2_MLP   (HSP_BLOCKS + 32)            // 553
#define S2_RANK  (S2_MLP + RANKB)             // 809
#define S2_WT    (S2_RANK + 320)              // 1129
#define S2_END   (S2_WT + 35)                 // 1164

typedef __attribute__((ext_vector_type(8))) short short8;
typedef __attribute__((ext_vector_type(4))) float floatx4;

// direct global->LDS staging (guide Common-mistake #1: compiler never auto-emits)
#define GLOAD16(dst, src) \
    __builtin_amdgcn_global_load_lds((const __attribute__((address_space(1))) void*)(src), \
                                     (__attribute__((address_space(3))) void*)(dst), 16, 0, 0)

// ---- workspace layout (in 4-byte units) ----
#define OFF_XB      0                                   // ushort[50048*640]
#define OFF_X1F     (XB_ROWS * XB_COLS / 2)             // hs partials region
#define OFF_X2F     (OFF_X1F + N_NODES * IN_F)          // degC/rsC fill this EXACTLY at N_CHK=64
#define OFF_DEGC    OFF_X2F                             // int[64*N] per-chunk counts (12.8MB)
#define OFF_RSC     (OFF_X2F + N_CHK * N_NODES)         // int[64*N] chunk scatter bases (12.8MB)
#define OFF_WT      (OFF_X2F + 2 * N_CHK * N_NODES)     // == OFF_X2F + N_NODES*IN_F (exact fit)
#define OFF_DSQRT   (OFF_WT + 40960)
#define OFF_HS      (OFF_DSQRT + N_NODES)
#define OFF_EF      (OFF_HS + NEIG * OUT_F)
#define OFF_COLSUM  (OFF_EF + NEIG)
#define OFF_COLSQ   (OFF_COLSUM + OUT_F)
#define OFF_PUB     (OFF_COLSQ + OUT_F)                 // u64[49] publish slots (128 ints)
#define OFF_ROWSTART (OFF_PUB + 8 * N_NODES)
#define OFF_CSR     (OFF_ROWSTART + N_NODES + 1)
#define OFF_BSUM    (OFF_CSR + N_EDGES)                 // 64 ints (legacy)
#define OFF_RANK    (OFF_BSUM + 64)                     // E ints
// end ~= 30.9M * 4B ~= 124 MB (< 128.3 MB proven in R0)

static __device__ inline unsigned short f2bf(float f) {
    union { float f; unsigned int u; } v; v.f = f;
    unsigned int r = (v.u + 0x7FFFu + ((v.u >> 16) & 1u)) >> 16;
    return (unsigned short)r;
}
static __device__ inline float bf2f(unsigned int u16) {
    union { unsigned int u; float f; } v; v.u = u16 << 16;
    return v.f;
}

// Branch-local shared regions OVERLAID in one union: hipcc SUMS separate
// __shared__ decls across divergent branches (R5 lesson: 51.7KB -> occupancy
// 5.9%, hs_partial 2.3x slower). Union -> 25KB = max, occupancy restored.
struct HsSm  { float sEv[32 * NEIG]; float sFt[32 * IN_F]; };   // 24576 B
struct MlpSm { float z0[2][HDIM]; float red[2][HDIM]; };        // 2048 B
union StageSm {
    HsSm hs;
    MlpSm mlp;
    unsigned int cnt[6250];                                     // 25000 B
};

// mega-fused stage2: hs_partial+feat2bf (0..520) | eigen-MLP (521..552) |
// LDS-rank (553..808) | Wt (809..1128) | zero stats+pub (1129..1163).
// R11 PMC (41.2us, Occ 16%): the 128-block rank section was a ~20us tail at
// 1 block/CU after hs drained — R15 doubles chunks (256 blocks x 12.5K edges)
// so rank covers all CUs and halves each block's serial chain.
// R9 LESSON: fusion only pays when it CUTS WORK. R8 LESSON: zero branch must
// not touch ef. rank: ZERO device atomics (R0-R4: memory-side RMW toll).
__global__ __launch_bounds__(256) void k_stage2(const float* __restrict__ evecs,
                                                const float* __restrict__ feat,
                                                float* __restrict__ partials,
                                                const float* __restrict__ evals,
                                                const float* __restrict__ ew0,
                                                const float* __restrict__ eb0,
                                                const float* __restrict__ ew1,
                                                const float* __restrict__ eb1,
                                                const float* __restrict__ ew2,
                                                const float* __restrict__ eb2,
                                                float* __restrict__ ef,
                                                int* __restrict__ degC,
                                                const int* __restrict__ dst,
                                                int* __restrict__ rank,
                                                const float* __restrict__ W,
                                                unsigned short* __restrict__ Xb,
                                                unsigned short* __restrict__ Wt,
                                                float* __restrict__ small,
                                                int* __restrict__ pubz) {
    __shared__ __align__(16) StageSm sm;
    int b = blockIdx.x;
    int t = threadIdx.x;
    if (b < HSP_BLOCKS) {
        // ---- hs partial: block handles 96 nodes; partial C[64][128] -> partials[b]
        // Also emits bf16(feat) to Xb slot0 for its 96 nodes (replaces prep-feat).
        float* sEv = sm.hs.sEv;
        float* sFt = sm.hs.sFt;
        int e0 = (t >> 5) * 8;
        int f0 = (t & 31) * 4;
        float acc[8][4];
#pragma unroll
        for (int r = 0; r < 8; ++r)
#pragma unroll
            for (int c = 0; c < 4; ++c) acc[r][c] = 0.0f;

        int n0 = b * HSP_NODES;
        for (int ch = 0; ch < HSP_NODES; ch += 32) {
            int base = n0 + ch;
            {
                int r = t >> 3, c = (t & 7) * 8;
                int n = base + r;
                float4 a, bb;
                if (n < N_NODES) {
                    a = *(const float4*)&evecs[(size_t)n * NEIG + c];
                    bb = *(const float4*)&evecs[(size_t)n * NEIG + c + 4];
                } else {
                    a = make_float4(0, 0, 0, 0); bb = a;
                }
                *(float4*)&sEv[r * NEIG + c] = a;
                *(float4*)&sEv[r * NEIG + c + 4] = bb;
            }
            {
                int r = t >> 3, c = (t & 7) * 16;
                int n = base + r;
#pragma unroll
                for (int q = 0; q < 4; ++q) {
                    float4 v = (n < N_NODES) ? *(const float4*)&feat[(size_t)n * IN_F + c + q * 4]
                                             : make_float4(0, 0, 0, 0);
                    *(float4*)&sFt[r * IN_F + c + q * 4] = v;
                    if (n < N_NODES) {
                        ushort4 o;
                        o.x = f2bf(v.x); o.y = f2bf(v.y); o.z = f2bf(v.z); o.w = f2bf(v.w);
                        *(ushort4*)&Xb[(size_t)n * XB_COLS + c + q * 4] = o;
                    }
                }
            }
            __syncthreads();
#pragma unroll 2
            for (int i = 0; i < 32; ++i) {
                float4 ev0 = *(float4*)&sEv[i * NEIG + e0];
                float4 ev1 = *(float4*)&sEv[i * NEIG + e0 + 4];
                float4 fv  = *(float4*)&sFt[i * IN_F + f0];
                float evv[8] = {ev0.x, ev0.y, ev0.z, ev0.w, ev1.x, ev1.y, ev1.z, ev1.w};
#pragma unroll
                for (int r = 0; r < 8; ++r) {
                    acc[r][0] += evv[r] * fv.x;
                    acc[r][1] += evv[r] * fv.y;
                    acc[r][2] += evv[r] * fv.z;
                    acc[r][3] += evv[r] * fv.w;
                }
            }
            __syncthreads();
        }
        float* p = &partials[(size_t)b * (NEIG * IN_F)];
#pragma unroll
        for (int r = 0; r < 8; ++r)
            *(float4*)&p[(e0 + r) * IN_F + f0] = make_float4(acc[r][0], acc[r][1], acc[r][2], acc[r][3]);
    } else if (b < S2_MLP) {
        // ---- eigen-MLP: 2 eigenvalues per 256-thread block
        int sub = t >> 7, j = t & 127;
        int i = (b - HSP_BLOCKS) * 2 + sub;
        float ev = evals[i];
        sm.mlp.z0[sub][j] = fmaxf(0.0f, ev * ew0[j] + eb0[j]);
        __syncthreads();
        float s0 = 0.f, s1 = 0.f, s2 = 0.f, s3 = 0.f;
        for (int h = 0; h < HDIM; h += 4) {
            s0 += sm.mlp.z0[sub][h]     * ew1[(h) * HDIM + j];
            s1 += sm.mlp.z0[sub][h + 1] * ew1[(h + 1) * HDIM + j];
            s2 += sm.mlp.z0[sub][h + 2] * ew1[(h + 2) * HDIM + j];
            s3 += sm.mlp.z0[sub][h + 3] * ew1[(h + 3) * HDIM + j];
        }
        float z1 = fmaxf(0.0f, eb1[j] + s0 + s1 + s2 + s3);
        sm.mlp.red[sub][j] = z1 * ew2[j];
        __syncthreads();
        for (int off = 64; off > 0; off >>= 1) {
            if (j < off) sm.mlp.red[sub][j] += sm.mlp.red[sub][j + off];
            __syncthreads();
        }
        if (j == 0) ef[i] = sm.mlp.red[sub][0] + eb2[0];
    } else if (b < S2_RANK) {
        // ---- LDS rank: block (g,c); g = node range [g*12500, +12500), c = edge chunk
        unsigned int* cnt = sm.cnt;             // 12500 u16 counters packed, 25 KB
        int rb = b - S2_MLP;
        int g = rb >> 6, c = rb & (N_CHK - 1);
        for (int k = t; k < 6250; k += 256) cnt[k] = 0;
        __syncthreads();
        int nlo = g * 12500;
        int ebase = c * CHUNK_E;
        for (int off0 = 0; off0 < CHUNK_E; off0 += 1024) {
            int d0[4];
#pragma unroll
            for (int k = 0; k < 4; ++k) {
                int o = off0 + k * 256 + t;
                d0[k] = (o < CHUNK_E) ? dst[ebase + o] : -1;
            }
#pragma unroll
            for (int k = 0; k < 4; ++k) {
                int o = off0 + k * 256 + t;
                int l = d0[k] - nlo;
                if ((unsigned)l < 12500u) {
                    unsigned sh = (l & 1) * 16;
                    unsigned old = atomicAdd(&cnt[l >> 1], 1u << sh);
                    rank[ebase + o] = ((old >> sh) & 0xFFFF) | (c << 24);
                }
            }
        }
        __syncthreads();
        // per-chunk counts for this range (each (c,node) written exactly once)
        for (int k = t; k < 6250; k += 256) {
            unsigned v = cnt[k];
            int n0 = nlo + k * 2;
            degC[(size_t)c * N_NODES + n0]     = (int)(v & 0xFFFF);
            degC[(size_t)c * N_NODES + n0 + 1] = (int)(v >> 16);
        }
    } else if (b < S2_WT) {
        // ---- W -> Wt bf16 (transposed)
        int tt = (b - S2_RANK) * 256 + t;        // [0, 81920)
        int k = tt >> 7, n = tt & 127;
        Wt[n * 640 + k] = f2bf(W[k * 128 + n]);
    } else {
        // ---- zero buffers written by LATER launches only: hs_small [0,8192),
        // colsum+colsq [8256,8512), pub. Skip ef [8192,8256): MLP writes it in
        // THIS kernel (R8 race).
        int i = (b - S2_WT) * 256 + t;
        const int HSZ = NEIG * OUT_F;            // 8192
        if (i < HSZ || (i >= HSZ + NEIG && i < HSZ + NEIG + 2 * OUT_F)) small[i] = 0.0f;
        if (i < 128) pubz[i] = 0;
    }
}

// fused: scan (blocks 0..48, with inline cross-block offset exchange via
// publish+spin — 177 blocks co-resident << capacity, spin cannot deadlock)
// | hs_reduce (49..176). NOTE (R13): publish+spin is fine HERE (tiny uniform
// blocks); it regressed 2.5x when grafted onto the throughput-bound gemm.
__global__ __launch_bounds__(1024) void k_stage3(int* __restrict__ degC,
                                                 int* __restrict__ row_start,
                                                 unsigned long long* __restrict__ pub,
                                                 const float* __restrict__ partials,
                                                 float* __restrict__ hs_small,
                                                 float* __restrict__ dsq,
                                                 int* __restrict__ rsC) {
    int b = blockIdx.x;
    int t = threadIdx.x;
    if (b < SCAN_BLK) {
        __shared__ int sd[1024];
        __shared__ int sOff;
        int i = b * 1024 + t;
        int total = 0;
        if (i < N_NODES) {
#pragma unroll 8
            for (int cc = 0; cc < N_CHK; ++cc)
                total += degC[(size_t)cc * N_NODES + i];
        }
        sd[t] = total;
        __syncthreads();
        for (int off = 1; off < 1024; off <<= 1) {
            int v = (t >= off) ? sd[t - off] : 0;
            __syncthreads();
            sd[t] += v;
            __syncthreads();
        }
        // publish this block's total (flag in bit 32), then gather all 49
        if (t == 0) {
            unsigned long long pv = (1ull << 32) | (unsigned long long)(unsigned)sd[1023];
            __hip_atomic_store(&pub[b], pv, __ATOMIC_RELEASE, __HIP_MEMORY_SCOPE_AGENT);
        }
        if (t < 64) {
            int tot = 0;
            if (t < SCAN_BLK) {
                unsigned long long v;
                do {
                    v = __hip_atomic_load(&pub[t], __ATOMIC_ACQUIRE, __HIP_MEMORY_SCOPE_AGENT);
                } while (!(v >> 32));
                tot = (int)(v & 0xffffffffu);
            }
            int contrib = (t < b) ? tot : 0;
            for (int off = 32; off > 0; off >>= 1) contrib += __shfl_down(contrib, off);
            if (t == 0) sOff = contrib;
        }
        __syncthreads();
        if (i < N_NODES) {
            int r = sd[t] - total + sOff;     // exclusive global prefix
            row_start[i] = r;
            int p = r;
            for (int cc = 0; cc < N_CHK; ++cc) {
                int v = degC[(size_t)cc * N_NODES + i];
                rsC[(size_t)cc * N_NODES + i] = p;
                p += v;
            }
            dsq[i] = rsqrtf((float)max(total, 1));
        }
        if (i == N_NODES - 1) row_start[N_NODES] = N_EDGES;
    } else {
        // split reduce: 8 elem-groups x 16 j-chunks; atomicAdd into pre-zeroed hs_small
        int b2 = b - SCAN_BLK;
        int grp = b2 & 7;
        int chunk = b2 >> 3;
        int idx = grp * 1024 + t;
        int j0 = chunk * RED_CHUNK;
        int j1 = min(j0 + RED_CHUNK, HSP_BLOCKS);
        float s = 0.0f;
        for (int j = j0; j < j1; ++j) s += partials[(size_t)j * (NEIG * IN_F) + idx];
        atomicAdd(&hs_small[idx], s);
    }
}

// fused: csr scatter (blocks 0..3124) | hs_apply (3125..4687)
__global__ __launch_bounds__(256) void k_stage6(const int* __restrict__ src,
                                                const int* __restrict__ dst,
                                                const int* __restrict__ rank,
                                                const int* __restrict__ rsC,
                                                int* __restrict__ csr_src,
                                                unsigned short* __restrict__ Xb,
                                                const float* __restrict__ evecs,
                                                const float* __restrict__ hs_small,
                                                const float* __restrict__ ef) {
    int b = blockIdx.x;
    int t = threadIdx.x;
    if (b < 3125) {
        int e = b * 256 + t;
        if (e < N_EDGES) {
            int rv = rank[e];
            int c = rv >> 24;
            csr_src[rsC[(size_t)c * N_NODES + dst[e]] + (rv & 0xFFFFFF)] = src[e];
        }
    } else {
        __shared__ float sShs[NEIG * HDIM];
        __shared__ float sEv[32 * NEIG];
        int n0 = (b - 3125) * 32;
        {
            float efv = ef[t >> 2];
            int pbase = t * 32;
#pragma unroll
            for (int q = 0; q < 8; ++q) {
                float4 v = *(const float4*)&hs_small[pbase + q * 4];
                v.x *= efv; v.y *= efv; v.z *= efv; v.w *= efv;
                *(float4*)&sShs[pbase + q * 4] = v;
            }
        }
        {
            int r = t >> 3, c = (t & 7) * 8;
            int n = n0 + r;
            float4 a, bb;
            if (n < N_NODES) {
                a = *(const float4*)&evecs[(size_t)n * NEIG + c];
                bb = *(const float4*)&evecs[(size_t)n * NEIG + c + 4];
            } else {
                a = make_float4(0, 0, 0, 0); bb = a;
            }
            *(float4*)&sEv[r * NEIG + c] = a;
            *(float4*)&sEv[r * NEIG + c + 4] = bb;
        }
        __syncthreads();
        int nb = (t >> 5) * 4;
        int f0 = (t & 31) * 4;
        float acc[4][4];
#pragma unroll
        for (int q = 0; q < 4; ++q)
#pragma unroll
            for (int c = 0; c < 4; ++c) acc[q][c] = 0.0f;
        for (int e = 0; e < NEIG; ++e) {
            float4 sv = *(float4*)&sShs[e * HDIM + f0];
#pragma unroll
            for (int q = 0; q < 4; ++q) {
                float evv = sEv[(nb + q) * NEIG + e];
                acc[q][0] += evv * sv.x;
                acc[q][1] += evv * sv.y;
                acc[q][2] += evv * sv.z;
                acc[q][3] += evv * sv.w;
            }
        }
#pragma unroll
        for (int q = 0; q < 4; ++q) {
            int n = n0 + nb + q;
            if (n < N_NODES) {
                ushort4 o;
                o.x = f2bf(acc[q][0]); o.y = f2bf(acc[q][1]);
                o.z = f2bf(acc[q][2]); o.w = f2bf(acc[q][3]);
                *(ushort4*)&Xb[(size_t)n * XB_COLS + 4 * IN_F + f0] = o;
            }
        }
    }
}

// One wave per node, all-bf16 state. 16x/8x/4x unrolled edge loop: up to 16
// independent 256 B row-loads in flight per wave. R2 LESSON: do NOT restructure
// into wider per-lane loads + lane-split — scratch demotion, 7x slower.
// R12 LESSON: pre-scaled source rows are a NET LOSS — gathers are
// row-fetch-bound and moving random reads off Xb costs gemm its L2/L3 warmth.
__global__ __launch_bounds__(256) void k_gather(const int* __restrict__ row_start,
                                                const int* __restrict__ csr_src,
                                                const float* __restrict__ dsq,
                                                const unsigned short* __restrict__ srcb,
                                                const unsigned short* __restrict__ prevb,
                                                const unsigned short* __restrict__ ppb,
                                                unsigned short* __restrict__ outb,
                                                const float* __restrict__ lm, int first) {
    int n = (blockIdx.x * 256 + threadIdx.x) >> 6;
    int lane = threadIdx.x & 63;
    if (n >= N_NODES) return;
    float rn = 2.0f / lm[0];
    float ax = 0.0f, ay = 0.0f;
    int beg = row_start[n], end = row_start[n + 1];
    int i = beg;
    for (; i + 16 <= end; i += 16) {
        int s[16]; float c[16]; unsigned int p[16];
#pragma unroll
        for (int j = 0; j < 16; ++j) s[j] = __builtin_amdgcn_readfirstlane(csr_src[i + j]);
#pragma unroll
        for (int j = 0; j < 16; ++j) c[j] = dsq[s[j]];
#pragma unroll
        for (int j = 0; j < 16; ++j)
            p[j] = *(const unsigned int*)&srcb[(size_t)s[j] * XB_COLS + lane * 2];
#pragma unroll
        for (int j = 0; j < 16; ++j) {
            ax += c[j] * bf2f(p[j] & 0xffffu);
            ay += c[j] * bf2f(p[j] >> 16);
        }
    }
    for (; i + 8 <= end; i += 8) {
        int s[8]; float c[8]; unsigned int p[8];
#pragma unroll
        for (int j = 0; j < 8; ++j) s[j] = __builtin_amdgcn_readfirstlane(csr_src[i + j]);
#pragma unroll
        for (int j = 0; j < 8; ++j) c[j] = dsq[s[j]];
#pragma unroll
        for (int j = 0; j < 8; ++j)
            p[j] = *(const unsigned int*)&srcb[(size_t)s[j] * XB_COLS + lane * 2];
#pragma unroll
        for (int j = 0; j < 8; ++j) {
            ax += c[j] * bf2f(p[j] & 0xffffu);
            ay += c[j] * bf2f(p[j] >> 16);
        }
    }
    for (; i + 4 <= end; i += 4) {
        int s[4]; float c[4]; unsigned int p[4];
#pragma unroll
        for (int j = 0; j < 4; ++j) s[j] = __builtin_amdgcn_readfirstlane(csr_src[i + j]);
#pragma unroll
        for (int j = 0; j < 4; ++j) c[j] = dsq[s[j]];
#pragma unroll
        for (int j = 0; j < 4; ++j)
            p[j] = *(const unsigned int*)&srcb[(size_t)s[j] * XB_COLS + lane * 2];
#pragma unroll
        for (int j = 0; j < 4; ++j) {
            ax += c[j] * bf2f(p[j] & 0xffffu);
            ay += c[j] * bf2f(p[j] >> 16);
        }
    }
    for (; i < end; ++i) {
        int s = __builtin_amdgcn_readfirstlane(csr_src[i]);
        float sc = dsq[s];
        unsigned int pv = *(const unsigned int*)&srcb[(size_t)s * XB_COLS + lane * 2];
        ax += sc * bf2f(pv & 0xffffu);
        ay += sc * bf2f(pv >> 16);
    }
    float ds = dsq[n];
    float a = (first ? -rn : -2.0f * rn) * ds;
    float b = first ? (rn - 1.0f) : 2.0f * (rn - 1.0f);
    unsigned int pu = *(const unsigned int*)&prevb[(size_t)n * XB_COLS + lane * 2];
    float rx = a * ax + b * bf2f(pu & 0xffffu);
    float ry = a * ay + b * bf2f(pu >> 16);
    if (ppb) {
        unsigned int qu = *(const unsigned int*)&ppb[(size_t)n * XB_COLS + lane * 2];
        rx -= bf2f(qu & 0xffffu);
        ry -= bf2f(qu >> 16);
    }
    unsigned int packed = (unsigned int)f2bf(rx) | ((unsigned int)f2bf(ry) << 16);
    *(unsigned int*)&outb[(size_t)n * XB_COLS + lane * 2] = packed;
}

// MFMA bf16 GEMM with fused BN column-stats (R11-proven structure: M=128,
// separate bn_apply — R13 LESSON: in-kernel all-arrive spin = 2x slower).
// Staging via global_load_lds width=16 (R14: neutral-to-slightly-positive).
__global__ __launch_bounds__(256) void k_gemm(const unsigned short* __restrict__ Xb,
                                              const unsigned short* __restrict__ Wt,
                                              const float* __restrict__ bias,
                                              float* __restrict__ out,
                                              float* __restrict__ colsum,
                                              float* __restrict__ colsq) {
    __shared__ unsigned short sA[128 * 32];
    __shared__ unsigned short sB[128 * 32];
    __shared__ float cs[4][OUT_F];
    __shared__ float cq[4][OUT_F];
    int tid = threadIdx.x;
    int wave = tid >> 6, lane = tid & 63;
    int quad = lane >> 4, m16 = lane & 15;
    int row0 = blockIdx.x * 128;

    floatx4 acc[2][8];
#pragma unroll
    for (int mt = 0; mt < 2; ++mt)
#pragma unroll
        for (int nt = 0; nt < 8; ++nt) acc[mt][nt] = (floatx4)(0.0f);

    int r  = tid >> 2;
    int c8 = (tid & 3) * 8;
    int gr0 = min(row0 + r, N_NODES - 1);
    int gr1 = min(row0 + r + 64, N_NODES - 1);

    unsigned short* dA0 = &sA[wave * 512];          // wave-uniform LDS bases
    unsigned short* dA1 = &sA[2048 + wave * 512];
    unsigned short* dB0 = &sB[wave * 512];
    unsigned short* dB1 = &sB[2048 + wave * 512];

    for (int k0 = 0; k0 < 640; k0 += 32) {
        GLOAD16(dA0, &Xb[(size_t)gr0 * XB_COLS + k0 + c8]);
        GLOAD16(dA1, &Xb[(size_t)gr1 * XB_COLS + k0 + c8]);
        GLOAD16(dB0, &Wt[r * 640 + k0 + c8]);
        GLOAD16(dB1, &Wt[(r + 64) * 640 + k0 + c8]);
        __syncthreads();
        short8 a0 = *(short8*)&sA[(wave * 32 + m16) * 32 + quad * 8];
        short8 a1 = *(short8*)&sA[(wave * 32 + 16 + m16) * 32 + quad * 8];
#pragma unroll
        for (int nt = 0; nt < 8; ++nt) {
            short8 b = *(short8*)&sB[(nt * 16 + m16) * 32 + quad * 8];
            acc[0][nt] = __builtin_amdgcn_mfma_f32_16x16x32_bf16(a0, b, acc[0][nt], 0, 0, 0);
            acc[1][nt] = __builtin_amdgcn_mfma_f32_16x16x32_bf16(a1, b, acc[1][nt], 0, 0, 0);
        }
        __syncthreads();
    }
#pragma unroll
    for (int nt = 0; nt < 8; ++nt) {
        int col = nt * 16 + m16;
        float bb = bias[col];
        float sv = 0.0f, sq = 0.0f;
#pragma unroll
        for (int mt = 0; mt < 2; ++mt) {
            int rbase = row0 + wave * 32 + mt * 16 + quad * 4;
#pragma unroll
            for (int reg = 0; reg < 4; ++reg) {
                int row = rbase + reg;
                if (row < N_NODES) {
                    float w = acc[mt][nt][reg] + bb;
                    out[(size_t)row * OUT_F + col] = w;
                    sv += w;
                    sq += w * w;
                }
            }
        }
        sv += __shfl_down(sv, 32); sq += __shfl_down(sq, 32);
        sv += __shfl_down(sv, 16); sq += __shfl_down(sq, 16);
        if (lane < 16) { cs[wave][col] = sv; cq[wave][col] = sq; }
    }
    __syncthreads();
    if (tid < OUT_F) {
        float s = cs[0][tid] + cs[1][tid] + cs[2][tid] + cs[3][tid];
        float q = cq[0][tid] + cq[1][tid] + cq[2][tid] + cq[3][tid];
        atomicAdd(&colsum[tid], s);
        atomicAdd(&colsq[tid], q);
    }
}

__global__ void k_bn_apply(float* __restrict__ out, const float* __restrict__ colsum,
                           const float* __restrict__ colsq, const float* __restrict__ gamma,
                           const float* __restrict__ beta) {
    int t = blockIdx.x * 256 + threadIdx.x;
    int n = t >> 5, c = t & 31;
    float4 v = *(float4*)&out[n * OUT_F + c * 4];
    float4 s = *(const float4*)&colsum[c * 4];
    float4 q = *(const float4*)&colsq[c * 4];
    float4 g = *(const float4*)&gamma[c * 4];
    float4 b = *(const float4*)&beta[c * 4];
    const float invN = 1.0f / (float)N_NODES;
    float mux = s.x * invN, muy = s.y * invN, muz = s.z * invN, muw = s.w * invN;
    float ix = rsqrtf(q.x * invN - mux * mux + BN_EPSF);
    float iy = rsqrtf(q.y * invN - muy * muy + BN_EPSF);
    float iz = rsqrtf(q.z * invN - muz * muz + BN_EPSF);
    float iw = rsqrtf(q.w * invN - muw * muw + BN_EPSF);
    v.x = fmaxf(0.0f, (v.x - mux) * ix * g.x + b.x);
    v.y = fmaxf(0.0f, (v.y - muy) * iy * g.y + b.y);
    v.z = fmaxf(0.0f, (v.z - muz) * iz * g.z + b.z);
    v.w = fmaxf(0.0f, (v.w - muw) * iw * g.w + b.w);
    *(float4*)&out[n * OUT_F + c * 4] = v;
}

extern "C" void kernel_launch(void* const* d_in, const int* in_sizes, int n_in,
                              void* d_out, int out_size, void* d_ws, size_t ws_size,
                              hipStream_t stream) {
    const float* feature    = (const float*)d_in[0];
    const float* lin_w      = (const float*)d_in[1];
    const float* lin_b      = (const float*)d_in[2];
    const float* ew0        = (const float*)d_in[3];
    const float* eb0        = (const float*)d_in[4];
    const float* ew1        = (const float*)d_in[5];
    const float* eb1        = (const float*)d_in[6];
    const float* ew2        = (const float*)d_in[7];
    const float* eb2        = (const float*)d_in[8];
    const float* bn_gamma   = (const float*)d_in[9];
    const float* bn_beta    = (const float*)d_in[10];
    const float* lambda_max = (const float*)d_in[11];
    const float* evecs      = (const float*)d_in[12];
    const float* evals      = (const float*)d_in[13];
    const int*   edge_src   = (const int*)d_in[14];
    const int*   edge_dst   = (const int*)d_in[15];

    float* out = (float*)d_out;
    float* ws  = (float*)d_ws;
    unsigned short* Xb = (unsigned short*)(ws + OFF_XB);
    unsigned short* Wt = (unsigned short*)(ws + OFF_WT);
    float* dsq      = ws + OFF_DSQRT;
    float* hs_small = ws + OFF_HS;
    float* ef       = ws + OFF_EF;
    float* colsum   = ws + OFF_COLSUM;
    float* colsq    = ws + OFF_COLSQ;
    int*   degC     = (int*)(ws + OFF_DEGC);
    int*   rsC      = (int*)(ws + OFF_RSC);
    int*   row_start= (int*)(ws + OFF_ROWSTART);
    int*   csr_src  = (int*)(ws + OFF_CSR);
    int*   rank     = (int*)(ws + OFF_RANK);
    int*   pubz     = (int*)(ws + OFF_PUB);
    unsigned long long* pub = (unsigned long long*)(ws + OFF_PUB);
    float* partials = ws + OFF_X1F;

    // ---- mega-fused: hs_partial+feat2bf | eigen-MLP | LDS-rank | Wt | zero ----
    k_stage2<<<S2_END, 256, 0, stream>>>(evecs, feature, partials,
                                         evals, ew0, eb0, ew1, eb1, ew2, eb2,
                                         ef, degC, edge_dst, rank,
                                         lin_w, Xb, Wt, hs_small, pubz);

    // ---- fused: scan (w/ inline cross-block offsets) | hs_reduce ----
    k_stage3<<<SCAN_BLK + 128, 1024, 0, stream>>>(degC, row_start, pub, partials,
                                                  hs_small, dsq, rsC);

    // ---- fused: csr scatter | hs_apply ----
    k_stage6<<<3125 + 1563, 256, 0, stream>>>(edge_src, edge_dst, rank, rsC, csr_src,
                                              Xb, evecs, hs_small, ef);

    // ---- Chebyshev recurrence (all-bf16 state in Xb column slots) ----
    const int GBLK = (N_NODES * 64 + 255) / 256;
    k_gather<<<GBLK, 256, 0, stream>>>(row_start, csr_src, dsq,
                                       Xb + 0, Xb + 0, (const unsigned short*)nullptr,
                                       Xb + IN_F, lambda_max, 1);
    k_gather<<<GBLK, 256, 0, stream>>>(row_start, csr_src, dsq,
                                       Xb + IN_F, Xb + IN_F, Xb + 0,
                                       Xb + 2 * IN_F, lambda_max, 0);
    k_gather<<<GBLK, 256, 0, stream>>>(row_start, csr_src, dsq,
                                       Xb + 2 * IN_F, Xb + 2 * IN_F, Xb + IN_F,
                                       Xb + 3 * IN_F, lambda_max, 0);

    // ---- MFMA linear (+BN stats) + BN apply ----
    k_gemm<<<(N_NODES + 127) / 128, 256, 0, stream>>>(Xb, Wt, lin_b, out, colsum, colsq);
    k_bn_apply<<<(N_NODES * 32) / 256, 256, 0, stream>>>(out, colsum, colsq, bn_gamma, bn_beta);
}

// Round 16
// 319.065 us; speedup vs baseline: 1.0289x; 1.0289x over previous
//
#include <hip/hip_runtime.h>

#define N_NODES 50000
#define N_EDGES 800000
#define IN_F    128
#define OUT_F   128
#define NEIG    64
#define HDIM    128
#define BN_EPSF 1e-5f
#define XB_ROWS 50048            // 50000 padded to 128
#define XB_COLS 640
#define SCAN_BLK 49              // ceil(50000/1024)
#define HSP_BLOCKS 521           // 521*96 >= 50000
#define HSP_NODES 96
#define RED_CHUNK 33             // ceil(521/16)
#define N_CHK 32                 // edge chunks (R15 LESSON: 64 regressed +6.6us —
                                 // scan/scatter merge traffic grew faster than the
                                 // rank tail shrank; 32 is the measured optimum)
#define N_RNG 4                  // node ranges (12500 nodes -> 25KB LDS counters)
#define RANKB (N_RNG * N_CHK)    // 128 rank blocks
#define CHUNK_E (N_EDGES / N_CHK) // 25000 edges per chunk

// stage2 block-range bounds (hs | mlp | rank | prep-wt | prep-zero)
#define S2_MLP   (HSP_BLOCKS + 32)            // 553
#define S2_RANK  (S2_MLP + RANKB)             // 681
#define S2_WT    (S2_RANK + 320)              // 1001
#define S2_END   (S2_WT + 35)                 // 1036

typedef __attribute__((ext_vector_type(8))) short short8;
typedef __attribute__((ext_vector_type(4))) float floatx4;

// direct global->LDS staging (guide Common-mistake #1: compiler never auto-emits)
#define GLOAD16(dst, src) \
    __builtin_amdgcn_global_load_lds((const __attribute__((address_space(1))) void*)(src), \
                                     (__attribute__((address_space(3))) void*)(dst), 16, 0, 0)

// ---- workspace layout (in 4-byte units) ----
#define OFF_XB      0                                   // ushort[50048*640]
#define OFF_X1F     (XB_ROWS * XB_COLS / 2)             // hs partials region
#define OFF_X2F     (OFF_X1F + N_NODES * IN_F)          // degC/rsC live here
#define OFF_DEGC    OFF_X2F                             // int[32*N] per-chunk counts
#define OFF_RSC     (OFF_X2F + N_CHK * N_NODES)         // int[32*N] chunk scatter bases
#define OFF_WT      (OFF_X2F + N_NODES * IN_F)          // ushort[640*128]
#define OFF_DSQRT   (OFF_WT + 40960)
#define OFF_HS      (OFF_DSQRT + N_NODES)
#define OFF_EF      (OFF_HS + NEIG * OUT_F)
#define OFF_COLSUM  (OFF_EF + NEIG)
#define OFF_COLSQ   (OFF_COLSUM + OUT_F)
#define OFF_PUB     (OFF_COLSQ + OUT_F)                 // u64[49] publish slots (128 ints)
#define OFF_ROWSTART (OFF_PUB + 8 * N_NODES)
#define OFF_CSR     (OFF_ROWSTART + N_NODES + 1)
#define OFF_BSUM    (OFF_CSR + N_EDGES)                 // 64 ints (legacy)
#define OFF_RANK    (OFF_BSUM + 64)                     // E ints
// end ~= 30.9M * 4B ~= 124 MB (< 128.3 MB proven in R0)

static __device__ inline unsigned short f2bf(float f) {
    union { float f; unsigned int u; } v; v.f = f;
    unsigned int r = (v.u + 0x7FFFu + ((v.u >> 16) & 1u)) >> 16;
    return (unsigned short)r;
}
static __device__ inline float bf2f(unsigned int u16) {
    union { unsigned int u; float f; } v; v.u = u16 << 16;
    return v.f;
}

// Branch-local shared regions OVERLAID in one union: hipcc SUMS separate
// __shared__ decls across divergent branches (R5 lesson: 51.7KB -> occupancy
// 5.9%, hs_partial 2.3x slower). Union -> 25KB = max, occupancy restored.
struct HsSm  { float sEv[32 * NEIG]; float sFt[32 * IN_F]; };   // 24576 B
struct MlpSm { float z0[2][HDIM]; float red[2][HDIM]; };        // 2048 B
union StageSm {
    HsSm hs;
    MlpSm mlp;
    unsigned int cnt[6250];                                     // 25000 B
};

// mega-fused stage2: hs_partial+feat2bf (0..520) | eigen-MLP (521..552) |
// LDS-rank (553..680) | Wt (681..1000) | zero stats+pub (1001..1035).
// R9 LESSON: launch gaps are ~0 — fusion only pays when it CUTS WORK (hs
// blocks emit bf16 Xb slot0 from the registers they stage: ~8us, R10/R11).
// R8 LESSON: zero branch must not touch ef (MLP writes it in THIS kernel).
// rank: ZERO device atomics (R0-R4: 800K memory-side RMWs = fixed ~40us toll),
// 128 blocks x 4-deep LDS-atomic ILP (R6: 64-block serial loop = latency tail).
__global__ __launch_bounds__(256) void k_stage2(const float* __restrict__ evecs,
                                                const float* __restrict__ feat,
                                                float* __restrict__ partials,
                                                const float* __restrict__ evals,
                                                const float* __restrict__ ew0,
                                                const float* __restrict__ eb0,
                                                const float* __restrict__ ew1,
                                                const float* __restrict__ eb1,
                                                const float* __restrict__ ew2,
                                                const float* __restrict__ eb2,
                                                float* __restrict__ ef,
                                                int* __restrict__ degC,
                                                const int* __restrict__ dst,
                                                int* __restrict__ rank,
                                                const float* __restrict__ W,
                                                unsigned short* __restrict__ Xb,
                                                unsigned short* __restrict__ Wt,
                                                float* __restrict__ small,
                                                int* __restrict__ pubz) {
    __shared__ __align__(16) StageSm sm;
    int b = blockIdx.x;
    int t = threadIdx.x;
    if (b < HSP_BLOCKS) {
        // ---- hs partial: block handles 96 nodes; partial C[64][128] -> partials[b]
        // Also emits bf16(feat) to Xb slot0 for its 96 nodes (replaces prep-feat).
        float* sEv = sm.hs.sEv;
        float* sFt = sm.hs.sFt;
        int e0 = (t >> 5) * 8;
        int f0 = (t & 31) * 4;
        float acc[8][4];
#pragma unroll
        for (int r = 0; r < 8; ++r)
#pragma unroll
            for (int c = 0; c < 4; ++c) acc[r][c] = 0.0f;

        int n0 = b * HSP_NODES;
        for (int ch = 0; ch < HSP_NODES; ch += 32) {
            int base = n0 + ch;
            {
                int r = t >> 3, c = (t & 7) * 8;
                int n = base + r;
                float4 a, bb;
                if (n < N_NODES) {
                    a = *(const float4*)&evecs[(size_t)n * NEIG + c];
                    bb = *(const float4*)&evecs[(size_t)n * NEIG + c + 4];
                } else {
                    a = make_float4(0, 0, 0, 0); bb = a;
                }
                *(float4*)&sEv[r * NEIG + c] = a;
                *(float4*)&sEv[r * NEIG + c + 4] = bb;
            }
            {
                int r = t >> 3, c = (t & 7) * 16;
                int n = base + r;
#pragma unroll
                for (int q = 0; q < 4; ++q) {
                    float4 v = (n < N_NODES) ? *(const float4*)&feat[(size_t)n * IN_F + c + q * 4]
                                             : make_float4(0, 0, 0, 0);
                    *(float4*)&sFt[r * IN_F + c + q * 4] = v;
                    if (n < N_NODES) {
                        ushort4 o;
                        o.x = f2bf(v.x); o.y = f2bf(v.y); o.z = f2bf(v.z); o.w = f2bf(v.w);
                        *(ushort4*)&Xb[(size_t)n * XB_COLS + c + q * 4] = o;
                    }
                }
            }
            __syncthreads();
#pragma unroll 2
            for (int i = 0; i < 32; ++i) {
                float4 ev0 = *(float4*)&sEv[i * NEIG + e0];
                float4 ev1 = *(float4*)&sEv[i * NEIG + e0 + 4];
                float4 fv  = *(float4*)&sFt[i * IN_F + f0];
                float evv[8] = {ev0.x, ev0.y, ev0.z, ev0.w, ev1.x, ev1.y, ev1.z, ev1.w};
#pragma unroll
                for (int r = 0; r < 8; ++r) {
                    acc[r][0] += evv[r] * fv.x;
                    acc[r][1] += evv[r] * fv.y;
                    acc[r][2] += evv[r] * fv.z;
                    acc[r][3] += evv[r] * fv.w;
                }
            }
            __syncthreads();
        }
        float* p = &partials[(size_t)b * (NEIG * IN_F)];
#pragma unroll
        for (int r = 0; r < 8; ++r)
            *(float4*)&p[(e0 + r) * IN_F + f0] = make_float4(acc[r][0], acc[r][1], acc[r][2], acc[r][3]);
    } else if (b < S2_MLP) {
        // ---- eigen-MLP: 2 eigenvalues per 256-thread block
        int sub = t >> 7, j = t & 127;
        int i = (b - HSP_BLOCKS) * 2 + sub;
        float ev = evals[i];
        sm.mlp.z0[sub][j] = fmaxf(0.0f, ev * ew0[j] + eb0[j]);
        __syncthreads();
        float s0 = 0.f, s1 = 0.f, s2 = 0.f, s3 = 0.f;
        for (int h = 0; h < HDIM; h += 4) {
            s0 += sm.mlp.z0[sub][h]     * ew1[(h) * HDIM + j];
            s1 += sm.mlp.z0[sub][h + 1] * ew1[(h + 1) * HDIM + j];
            s2 += sm.mlp.z0[sub][h + 2] * ew1[(h + 2) * HDIM + j];
            s3 += sm.mlp.z0[sub][h + 3] * ew1[(h + 3) * HDIM + j];
        }
        float z1 = fmaxf(0.0f, eb1[j] + s0 + s1 + s2 + s3);
        sm.mlp.red[sub][j] = z1 * ew2[j];
        __syncthreads();
        for (int off = 64; off > 0; off >>= 1) {
            if (j < off) sm.mlp.red[sub][j] += sm.mlp.red[sub][j + off];
            __syncthreads();
        }
        if (j == 0) ef[i] = sm.mlp.red[sub][0] + eb2[0];
    } else if (b < S2_RANK) {
        // ---- LDS rank: block (g,c); g = node range [g*12500, +12500), c = edge chunk
        unsigned int* cnt = sm.cnt;             // 12500 u16 counters packed, 25 KB
        int rb = b - S2_MLP;
        int g = rb >> 5, c = rb & (N_CHK - 1);
        for (int k = t; k < 6250; k += 256) cnt[k] = 0;
        __syncthreads();
        int nlo = g * 12500;
        int ebase = c * CHUNK_E;
        for (int off0 = 0; off0 < CHUNK_E; off0 += 1024) {
            int d0[4];
#pragma unroll
            for (int k = 0; k < 4; ++k) {
                int o = off0 + k * 256 + t;
                d0[k] = (o < CHUNK_E) ? dst[ebase + o] : -1;
            }
#pragma unroll
            for (int k = 0; k < 4; ++k) {
                int o = off0 + k * 256 + t;
                int l = d0[k] - nlo;
                if ((unsigned)l < 12500u) {
                    unsigned sh = (l & 1) * 16;
                    unsigned old = atomicAdd(&cnt[l >> 1], 1u << sh);
                    rank[ebase + o] = ((old >> sh) & 0xFFFF) | (c << 24);
                }
            }
        }
        __syncthreads();
        // per-chunk counts for this range (each (c,node) written exactly once)
        for (int k = t; k < 6250; k += 256) {
            unsigned v = cnt[k];
            int n0 = nlo + k * 2;
            degC[(size_t)c * N_NODES + n0]     = (int)(v & 0xFFFF);
            degC[(size_t)c * N_NODES + n0 + 1] = (int)(v >> 16);
        }
    } else if (b < S2_WT) {
        // ---- W -> Wt bf16 (transposed)
        int tt = (b - S2_RANK) * 256 + t;        // [0, 81920)
        int k = tt >> 7, n = tt & 127;
        Wt[n * 640 + k] = f2bf(W[k * 128 + n]);
    } else {
        // ---- zero buffers written by LATER launches only: hs_small [0,8192),
        // colsum+colsq [8256,8512), pub. Skip ef [8192,8256): MLP writes it in
        // THIS kernel (R8 race).
        int i = (b - S2_WT) * 256 + t;
        const int HSZ = NEIG * OUT_F;            // 8192
        if (i < HSZ || (i >= HSZ + NEIG && i < HSZ + NEIG + 2 * OUT_F)) small[i] = 0.0f;
        if (i < 128) pubz[i] = 0;
    }
}

// fused: scan (blocks 0..48, with inline cross-block offset exchange via
// publish+spin — 177 blocks co-resident << capacity, spin cannot deadlock)
// | hs_reduce (49..176). NOTE (R13): publish+spin is fine HERE (tiny uniform
// blocks); it regressed 2.5x when grafted onto the throughput-bound gemm.
__global__ __launch_bounds__(1024) void k_stage3(int* __restrict__ degC,
                                                 int* __restrict__ row_start,
                                                 unsigned long long* __restrict__ pub,
                                                 const float* __restrict__ partials,
                                                 float* __restrict__ hs_small,
                                                 float* __restrict__ dsq,
                                                 int* __restrict__ rsC) {
    int b = blockIdx.x;
    int t = threadIdx.x;
    if (b < SCAN_BLK) {
        __shared__ int sd[1024];
        __shared__ int sOff;
        int i = b * 1024 + t;
        int total = 0;
        if (i < N_NODES) {
#pragma unroll 8
            for (int cc = 0; cc < N_CHK; ++cc)
                total += degC[(size_t)cc * N_NODES + i];
        }
        sd[t] = total;
        __syncthreads();
        for (int off = 1; off < 1024; off <<= 1) {
            int v = (t >= off) ? sd[t - off] : 0;
            __syncthreads();
            sd[t] += v;
            __syncthreads();
        }
        // publish this block's total (flag in bit 32), then gather all 49
        if (t == 0) {
            unsigned long long pv = (1ull << 32) | (unsigned long long)(unsigned)sd[1023];
            __hip_atomic_store(&pub[b], pv, __ATOMIC_RELEASE, __HIP_MEMORY_SCOPE_AGENT);
        }
        if (t < 64) {
            int tot = 0;
            if (t < SCAN_BLK) {
                unsigned long long v;
                do {
                    v = __hip_atomic_load(&pub[t], __ATOMIC_ACQUIRE, __HIP_MEMORY_SCOPE_AGENT);
                } while (!(v >> 32));
                tot = (int)(v & 0xffffffffu);
            }
            int contrib = (t < b) ? tot : 0;
            for (int off = 32; off > 0; off >>= 1) contrib += __shfl_down(contrib, off);
            if (t == 0) sOff = contrib;
        }
        __syncthreads();
        if (i < N_NODES) {
            int r = sd[t] - total + sOff;     // exclusive global prefix
            row_start[i] = r;
            int p = r;
            for (int cc = 0; cc < N_CHK; ++cc) {
                int v = degC[(size_t)cc * N_NODES + i];
                rsC[(size_t)cc * N_NODES + i] = p;
                p += v;
            }
            dsq[i] = rsqrtf((float)max(total, 1));
        }
        if (i == N_NODES - 1) row_start[N_NODES] = N_EDGES;
    } else {
        // split reduce: 8 elem-groups x 16 j-chunks; atomicAdd into pre-zeroed hs_small
        int b2 = b - SCAN_BLK;
        int grp = b2 & 7;
        int chunk = b2 >> 3;
        int idx = grp * 1024 + t;
        int j0 = chunk * RED_CHUNK;
        int j1 = min(j0 + RED_CHUNK, HSP_BLOCKS);
        float s = 0.0f;
        for (int j = j0; j < j1; ++j) s += partials[(size_t)j * (NEIG * IN_F) + idx];
        atomicAdd(&hs_small[idx], s);
    }
}

// fused: csr scatter (blocks 0..3124) | hs_apply (3125..4687)
__global__ __launch_bounds__(256) void k_stage6(const int* __restrict__ src,
                                                const int* __restrict__ dst,
                                                const int* __restrict__ rank,
                                                const int* __restrict__ rsC,
                                                int* __restrict__ csr_src,
                                                unsigned short* __restrict__ Xb,
                                                const float* __restrict__ evecs,
                                                const float* __restrict__ hs_small,
                                                const float* __restrict__ ef) {
    int b = blockIdx.x;
    int t = threadIdx.x;
    if (b < 3125) {
        int e = b * 256 + t;
        if (e < N_EDGES) {
            int rv = rank[e];
            int c = rv >> 24;
            csr_src[rsC[(size_t)c * N_NODES + dst[e]] + (rv & 0xFFFFFF)] = src[e];
        }
    } else {
        __shared__ float sShs[NEIG * HDIM];
        __shared__ float sEv[32 * NEIG];
        int n0 = (b - 3125) * 32;
        {
            float efv = ef[t >> 2];
            int pbase = t * 32;
#pragma unroll
            for (int q = 0; q < 8; ++q) {
                float4 v = *(const float4*)&hs_small[pbase + q * 4];
                v.x *= efv; v.y *= efv; v.z *= efv; v.w *= efv;
                *(float4*)&sShs[pbase + q * 4] = v;
            }
        }
        {
            int r = t >> 3, c = (t & 7) * 8;
            int n = n0 + r;
            float4 a, bb;
            if (n < N_NODES) {
                a = *(const float4*)&evecs[(size_t)n * NEIG + c];
                bb = *(const float4*)&evecs[(size_t)n * NEIG + c + 4];
            } else {
                a = make_float4(0, 0, 0, 0); bb = a;
            }
            *(float4*)&sEv[r * NEIG + c] = a;
            *(float4*)&sEv[r * NEIG + c + 4] = bb;
        }
        __syncthreads();
        int nb = (t >> 5) * 4;
        int f0 = (t & 31) * 4;
        float acc[4][4];
#pragma unroll
        for (int q = 0; q < 4; ++q)
#pragma unroll
            for (int c = 0; c < 4; ++c) acc[q][c] = 0.0f;
        for (int e = 0; e < NEIG; ++e) {
            float4 sv = *(float4*)&sShs[e * HDIM + f0];
#pragma unroll
            for (int q = 0; q < 4; ++q) {
                float evv = sEv[(nb + q) * NEIG + e];
                acc[q][0] += evv * sv.x;
                acc[q][1] += evv * sv.y;
                acc[q][2] += evv * sv.z;
                acc[q][3] += evv * sv.w;
            }
        }
#pragma unroll
        for (int q = 0; q < 4; ++q) {
            int n = n0 + nb + q;
            if (n < N_NODES) {
                ushort4 o;
                o.x = f2bf(acc[q][0]); o.y = f2bf(acc[q][1]);
                o.z = f2bf(acc[q][2]); o.w = f2bf(acc[q][3]);
                *(ushort4*)&Xb[(size_t)n * XB_COLS + 4 * IN_F + f0] = o;
            }
        }
    }
}

// One wave per node, all-bf16 state. 16x/8x/4x unrolled edge loop: up to 16
// independent 256 B row-loads in flight per wave. R2 LESSON: do NOT restructure
// into wider per-lane loads + lane-split — scratch demotion, 7x slower.
// R12 LESSON: pre-scaled source rows are a NET LOSS — gathers are
// row-fetch-bound and moving random reads off Xb costs gemm its L2/L3 warmth.
__global__ __launch_bounds__(256) void k_gather(const int* __restrict__ row_start,
                                                const int* __restrict__ csr_src,
                                                const float* __restrict__ dsq,
                                                const unsigned short* __restrict__ srcb,
                                                const unsigned short* __restrict__ prevb,
                                                const unsigned short* __restrict__ ppb,
                                                unsigned short* __restrict__ outb,
                                                const float* __restrict__ lm, int first) {
    int n = (blockIdx.x * 256 + threadIdx.x) >> 6;
    int lane = threadIdx.x & 63;
    if (n >= N_NODES) return;
    float rn = 2.0f / lm[0];
    float ax = 0.0f, ay = 0.0f;
    int beg = row_start[n], end = row_start[n + 1];
    int i = beg;
    for (; i + 16 <= end; i += 16) {
        int s[16]; float c[16]; unsigned int p[16];
#pragma unroll
        for (int j = 0; j < 16; ++j) s[j] = __builtin_amdgcn_readfirstlane(csr_src[i + j]);
#pragma unroll
        for (int j = 0; j < 16; ++j) c[j] = dsq[s[j]];
#pragma unroll
        for (int j = 0; j < 16; ++j)
            p[j] = *(const unsigned int*)&srcb[(size_t)s[j] * XB_COLS + lane * 2];
#pragma unroll
        for (int j = 0; j < 16; ++j) {
            ax += c[j] * bf2f(p[j] & 0xffffu);
            ay += c[j] * bf2f(p[j] >> 16);
        }
    }
    for (; i + 8 <= end; i += 8) {
        int s[8]; float c[8]; unsigned int p[8];
#pragma unroll
        for (int j = 0; j < 8; ++j) s[j] = __builtin_amdgcn_readfirstlane(csr_src[i + j]);
#pragma unroll
        for (int j = 0; j < 8; ++j) c[j] = dsq[s[j]];
#pragma unroll
        for (int j = 0; j < 8; ++j)
            p[j] = *(const unsigned int*)&srcb[(size_t)s[j] * XB_COLS + lane * 2];
#pragma unroll
        for (int j = 0; j < 8; ++j) {
            ax += c[j] * bf2f(p[j] & 0xffffu);
            ay += c[j] * bf2f(p[j] >> 16);
        }
    }
    for (; i + 4 <= end; i += 4) {
        int s[4]; float c[4]; unsigned int p[4];
#pragma unroll
        for (int j = 0; j < 4; ++j) s[j] = __builtin_amdgcn_readfirstlane(csr_src[i + j]);
#pragma unroll
        for (int j = 0; j < 4; ++j) c[j] = dsq[s[j]];
#pragma unroll
        for (int j = 0; j < 4; ++j)
            p[j] = *(const unsigned int*)&srcb[(size_t)s[j] * XB_COLS + lane * 2];
#pragma unroll
        for (int j = 0; j < 4; ++j) {
            ax += c[j] * bf2f(p[j] & 0xffffu);
            ay += c[j] * bf2f(p[j] >> 16);
        }
    }
    for (; i < end; ++i) {
        int s = __builtin_amdgcn_readfirstlane(csr_src[i]);
        float sc = dsq[s];
        unsigned int pv = *(const unsigned int*)&srcb[(size_t)s * XB_COLS + lane * 2];
        ax += sc * bf2f(pv & 0xffffu);
        ay += sc * bf2f(pv >> 16);
    }
    float ds = dsq[n];
    float a = (first ? -rn : -2.0f * rn) * ds;
    float b = first ? (rn - 1.0f) : 2.0f * (rn - 1.0f);
    unsigned int pu = *(const unsigned int*)&prevb[(size_t)n * XB_COLS + lane * 2];
    float rx = a * ax + b * bf2f(pu & 0xffffu);
    float ry = a * ay + b * bf2f(pu >> 16);
    if (ppb) {
        unsigned int qu = *(const unsigned int*)&ppb[(size_t)n * XB_COLS + lane * 2];
        rx -= bf2f(qu & 0xffffu);
        ry -= bf2f(qu >> 16);
    }
    unsigned int packed = (unsigned int)f2bf(rx) | ((unsigned int)f2bf(ry) << 16);
    *(unsigned int*)&outb[(size_t)n * XB_COLS + lane * 2] = packed;
}

// MFMA bf16 GEMM with fused BN column-stats (R11-proven structure: M=128,
// separate bn_apply — R13 LESSON: in-kernel all-arrive spin = 2x slower).
// Staging via global_load_lds width=16 (R14: neutral-to-slightly-positive).
__global__ __launch_bounds__(256) void k_gemm(const unsigned short* __restrict__ Xb,
                                              const unsigned short* __restrict__ Wt,
                                              const float* __restrict__ bias,
                                              float* __restrict__ out,
                                              float* __restrict__ colsum,
                                              float* __restrict__ colsq) {
    __shared__ unsigned short sA[128 * 32];
    __shared__ unsigned short sB[128 * 32];
    __shared__ float cs[4][OUT_F];
    __shared__ float cq[4][OUT_F];
    int tid = threadIdx.x;
    int wave = tid >> 6, lane = tid & 63;
    int quad = lane >> 4, m16 = lane & 15;
    int row0 = blockIdx.x * 128;

    floatx4 acc[2][8];
#pragma unroll
    for (int mt = 0; mt < 2; ++mt)
#pragma unroll
        for (int nt = 0; nt < 8; ++nt) acc[mt][nt] = (floatx4)(0.0f);

    int r  = tid >> 2;
    int c8 = (tid & 3) * 8;
    int gr0 = min(row0 + r, N_NODES - 1);
    int gr1 = min(row0 + r + 64, N_NODES - 1);

    unsigned short* dA0 = &sA[wave * 512];          // wave-uniform LDS bases
    unsigned short* dA1 = &sA[2048 + wave * 512];
    unsigned short* dB0 = &sB[wave * 512];
    unsigned short* dB1 = &sB[2048 + wave * 512];

    for (int k0 = 0; k0 < 640; k0 += 32) {
        GLOAD16(dA0, &Xb[(size_t)gr0 * XB_COLS + k0 + c8]);
        GLOAD16(dA1, &Xb[(size_t)gr1 * XB_COLS + k0 + c8]);
        GLOAD16(dB0, &Wt[r * 640 + k0 + c8]);
        GLOAD16(dB1, &Wt[(r + 64) * 640 + k0 + c8]);
        __syncthreads();
        short8 a0 = *(short8*)&sA[(wave * 32 + m16) * 32 + quad * 8];
        short8 a1 = *(short8*)&sA[(wave * 32 + 16 + m16) * 32 + quad * 8];
#pragma unroll
        for (int nt = 0; nt < 8; ++nt) {
            short8 b = *(short8*)&sB[(nt * 16 + m16) * 32 + quad * 8];
            acc[0][nt] = __builtin_amdgcn_mfma_f32_16x16x32_bf16(a0, b, acc[0][nt], 0, 0, 0);
            acc[1][nt] = __builtin_amdgcn_mfma_f32_16x16x32_bf16(a1, b, acc[1][nt], 0, 0, 0);
        }
        __syncthreads();
    }
#pragma unroll
    for (int nt = 0; nt < 8; ++nt) {
        int col = nt * 16 + m16;
        float bb = bias[col];
        float sv = 0.0f, sq = 0.0f;
#pragma unroll
        for (int mt = 0; mt < 2; ++mt) {
            int rbase = row0 + wave * 32 + mt * 16 + quad * 4;
#pragma unroll
            for (int reg = 0; reg < 4; ++reg) {
                int row = rbase + reg;
                if (row < N_NODES) {
                    float w = acc[mt][nt][reg] + bb;
                    out[(size_t)row * OUT_F + col] = w;
                    sv += w;
                    sq += w * w;
                }
            }
        }
        sv += __shfl_down(sv, 32); sq += __shfl_down(sq, 32);
        sv += __shfl_down(sv, 16); sq += __shfl_down(sq, 16);
        if (lane < 16) { cs[wave][col] = sv; cq[wave][col] = sq; }
    }
    __syncthreads();
    if (tid < OUT_F) {
        float s = cs[0][tid] + cs[1][tid] + cs[2][tid] + cs[3][tid];
        float q = cq[0][tid] + cq[1][tid] + cq[2][tid] + cq[3][tid];
        atomicAdd(&colsum[tid], s);
        atomicAdd(&colsq[tid], q);
    }
}

__global__ void k_bn_apply(float* __restrict__ out, const float* __restrict__ colsum,
                           const float* __restrict__ colsq, const float* __restrict__ gamma,
                           const float* __restrict__ beta) {
    int t = blockIdx.x * 256 + threadIdx.x;
    int n = t >> 5, c = t & 31;
    float4 v = *(float4*)&out[n * OUT_F + c * 4];
    float4 s = *(const float4*)&colsum[c * 4];
    float4 q = *(const float4*)&colsq[c * 4];
    float4 g = *(const float4*)&gamma[c * 4];
    float4 b = *(const float4*)&beta[c * 4];
    const float invN = 1.0f / (float)N_NODES;
    float mux = s.x * invN, muy = s.y * invN, muz = s.z * invN, muw = s.w * invN;
    float ix = rsqrtf(q.x * invN - mux * mux + BN_EPSF);
    float iy = rsqrtf(q.y * invN - muy * muy + BN_EPSF);
    float iz = rsqrtf(q.z * invN - muz * muz + BN_EPSF);
    float iw = rsqrtf(q.w * invN - muw * muw + BN_EPSF);
    v.x = fmaxf(0.0f, (v.x - mux) * ix * g.x + b.x);
    v.y = fmaxf(0.0f, (v.y - muy) * iy * g.y + b.y);
    v.z = fmaxf(0.0f, (v.z - muz) * iz * g.z + b.z);
    v.w = fmaxf(0.0f, (v.w - muw) * iw * g.w + b.w);
    *(float4*)&out[n * OUT_F + c * 4] = v;
}

extern "C" void kernel_launch(void* const* d_in, const int* in_sizes, int n_in,
                              void* d_out, int out_size, void* d_ws, size_t ws_size,
                              hipStream_t stream) {
    const float* feature    = (const float*)d_in[0];
    const float* lin_w      = (const float*)d_in[1];
    const float* lin_b      = (const float*)d_in[2];
    const float* ew0        = (const float*)d_in[3];
    const float* eb0        = (const float*)d_in[4];
    const float* ew1        = (const float*)d_in[5];
    const float* eb1        = (const float*)d_in[6];
    const float* ew2        = (const float*)d_in[7];
    const float* eb2        = (const float*)d_in[8];
    const float* bn_gamma   = (const float*)d_in[9];
    const float* bn_beta    = (const float*)d_in[10];
    const float* lambda_max = (const float*)d_in[11];
    const float* evecs      = (const float*)d_in[12];
    const float* evals      = (const float*)d_in[13];
    const int*   edge_src   = (const int*)d_in[14];
    const int*   edge_dst   = (const int*)d_in[15];

    float* out = (float*)d_out;
    float* ws  = (float*)d_ws;
    unsigned short* Xb = (unsigned short*)(ws + OFF_XB);
    unsigned short* Wt = (unsigned short*)(ws + OFF_WT);
    float* dsq      = ws + OFF_DSQRT;
    float* hs_small = ws + OFF_HS;
    float* ef       = ws + OFF_EF;
    float* colsum   = ws + OFF_COLSUM;
    float* colsq    = ws + OFF_COLSQ;
    int*   degC     = (int*)(ws + OFF_DEGC);
    int*   rsC      = (int*)(ws + OFF_RSC);
    int*   row_start= (int*)(ws + OFF_ROWSTART);
    int*   csr_src  = (int*)(ws + OFF_CSR);
    int*   rank     = (int*)(ws + OFF_RANK);
    int*   pubz     = (int*)(ws + OFF_PUB);
    unsigned long long* pub = (unsigned long long*)(ws + OFF_PUB);
    float* partials = ws + OFF_X1F;

    // ---- mega-fused: hs_partial+feat2bf | eigen-MLP | LDS-rank | Wt | zero ----
    k_stage2<<<S2_END, 256, 0, stream>>>(evecs, feature, partials,
                                         evals, ew0, eb0, ew1, eb1, ew2, eb2,
                                         ef, degC, edge_dst, rank,
                                         lin_w, Xb, Wt, hs_small, pubz);

    // ---- fused: scan (w/ inline cross-block offsets) | hs_reduce ----
    k_stage3<<<SCAN_BLK + 128, 1024, 0, stream>>>(degC, row_start, pub, partials,
                                                  hs_small, dsq, rsC);

    // ---- fused: csr scatter | hs_apply ----
    k_stage6<<<3125 + 1563, 256, 0, stream>>>(edge_src, edge_dst, rank, rsC, csr_src,
                                              Xb, evecs, hs_small, ef);

    // ---- Chebyshev recurrence (all-bf16 state in Xb column slots) ----
    const int GBLK = (N_NODES * 64 + 255) / 256;
    k_gather<<<GBLK, 256, 0, stream>>>(row_start, csr_src, dsq,
                                       Xb + 0, Xb + 0, (const unsigned short*)nullptr,
                                       Xb + IN_F, lambda_max, 1);
    k_gather<<<GBLK, 256, 0, stream>>>(row_start, csr_src, dsq,
                                       Xb + IN_F, Xb + IN_F, Xb + 0,
                                       Xb + 2 * IN_F, lambda_max, 0);
    k_gather<<<GBLK, 256, 0, stream>>>(row_start, csr_src, dsq,
                                       Xb + 2 * IN_F, Xb + 2 * IN_F, Xb + IN_F,
                                       Xb + 3 * IN_F, lambda_max, 0);

    // ---- MFMA linear (+BN stats) + BN apply ----
    k_gemm<<<(N_NODES + 127) / 128, 256, 0, stream>>>(Xb, Wt, lin_b, out, colsum, colsq);
    k_bn_apply<<<(N_NODES * 32) / 256, 256, 0, stream>>>(out, colsum, colsq, bn_gamma, bn_beta);
}